// Round 4
// baseline (179.451 us; speedup 1.0000x reference)
//
#include <hip/hip_runtime.h>

#define EDGES   262144
#define CTPB    256
#define SCHUNK  256
#define NINT    2048   // 32 rblocks * 8 schunks * 8 segments
#define NFLT    (EDGES / CTPB)   // 1024
#define NPRI    16     // 4096 nodes / 256
#define NBLK    (NINT + NFLT + NPRI)

typedef float v2f __attribute__((ext_vector_type(2)));

__device__ __forceinline__ float fast_rsq(float x) { return __builtin_amdgcn_rsqf(x); }

// ---- forced VOP3P packed fp32 (backend won't form these from <2 x float>) ----
__device__ __forceinline__ v2f pk_fma(v2f a, v2f b, v2f c) {
    v2f d;
    asm("v_pk_fma_f32 %0, %1, %2, %3" : "=v"(d) : "v"(a), "v"(b), "v"(c));
    return d;
}
__device__ __forceinline__ v2f pk_mul(v2f a, v2f b) {
    v2f d;
    asm("v_pk_mul_f32 %0, %1, %2" : "=v"(d) : "v"(a), "v"(b));
    return d;
}
__device__ __forceinline__ v2f pk_add(v2f a, v2f b) {
    v2f d;
    asm("v_pk_add_f32 %0, %1, %2" : "=v"(d) : "v"(a), "v"(b));
    return d;
}

// Odd degree-9 erf approx on clamped |x|<=2; max abs err ~7e-4/-4e-3 sat.
__device__ __forceinline__ v2f erf2(v2f x, v2f c4, v2f c3, v2f c2, v2f c1, v2f c0) {
    v2f c;
    c.x = __builtin_amdgcn_fmed3f(x.x, -2.0f, 2.0f);
    c.y = __builtin_amdgcn_fmed3f(x.y, -2.0f, 2.0f);
    v2f t = pk_mul(c, c);
    v2f p = pk_fma(t, c4, c3);
    p = pk_fma(t, p, c2);
    p = pk_fma(t, p, c1);
    p = pk_fma(t, p, c0);
    return pk_mul(c, p);
}

template <int NW>
__device__ __forceinline__ float block_reduce(float v, float* sm) {
    #pragma unroll
    for (int o = 32; o > 0; o >>= 1) v += __shfl_down(v, o, 64);
    int lane = threadIdx.x & 63;
    int wid  = threadIdx.x >> 6;
    if (lane == 0) sm[wid] = v;
    __syncthreads();
    float r = 0.0f;
    if (threadIdx.x == 0) {
        #pragma unroll
        for (int w = 0; w < NW; ++w) r += sm[w];
    }
    return r;
}

__global__ __launch_bounds__(CTPB) void k_mega(const float* __restrict__ Z,
        const float* __restrict__ ts, const int* __restrict__ snd,
        const int* __restrict__ rcv, const int* __restrict__ nodes,
        const int* __restrict__ su, const float* __restrict__ cp,
        float* __restrict__ part, int mode) {
    __shared__ v2f sZx[SCHUNK / 2];
    __shared__ v2f sZy[SCHUNK / 2];
    __shared__ v2f sDx[SCHUNK / 2];
    __shared__ v2f sDy[SCHUNK / 2];
    __shared__ float smr[CTPB / 64];
    const int bid = blockIdx.x;
    const int tid = threadIdx.x;
    float r;
    int slot;

    if (bid < NINT) {
        // ---- integral over sender-chunk x receiver-block pairs ----
        // w = Zs0-Zr0, v = DZs-DZr; D=|w|^2, S=|v|^2, g=<v,w>*rsq(S)=-u
        // term = exp(g^2-D)*rsq*(erf(rt+g)-erf(g)), rt=sqrt(S)
        const int k  = bid >> 8;
        const int sc = (bid >> 5) & 7;
        const int rb = bid & 31;
        {
            int n = su[sc * SCHUNK + tid];
            const float* z = Z + n * 18 + k;
            float zx = z[0], zy = z[9];
            ((float*)sZx)[tid] = zx;
            ((float*)sZy)[tid] = zy;
            ((float*)sDx)[tid] = z[1] - zx;
            ((float*)sDy)[tid] = z[10] - zy;
        }
        const float* zr = Z + (rb * CTPB + tid) * 18 + k;
        float rzx = zr[0], rzy = zr[9];
        float rdx = zr[1] - rzx, rdy = zr[10] - rzy;
        v2f nrzx = {-rzx, -rzx}, nrzy = {-rzy, -rzy};
        v2f nrdx = {-rdx, -rdx}, nrdy = {-rdy, -rdy};
        const v2f cm1 = {-1.0f, -1.0f};
        const v2f c4 = { 0.0011996f,  0.0011996f};
        const v2f c3 = {-0.0165450f, -0.0165450f};
        const v2f c2 = { 0.100174f,   0.100174f};
        const v2f c1 = {-0.370237f,  -0.370237f};
        const v2f c0 = { 1.127915f,   1.127915f};
        __syncthreads();

        float s0 = 0.0f, s1 = 0.0f;
        #pragma unroll 2
        for (int i = 0; i < SCHUNK / 2; ++i) {
            v2f wx = pk_add(sZx[i], nrzx);
            v2f wy = pk_add(sZy[i], nrzy);
            v2f vx = pk_add(sDx[i], nrdx);
            v2f vy = pk_add(sDy[i], nrdy);
            v2f D  = pk_fma(wy, wy, pk_mul(wx, wx));
            v2f S  = pk_fma(vy, vy, pk_mul(vx, vx));
            v2f mc = pk_fma(vy, wy, pk_mul(vx, wx));   // <v,w> = -C
            v2f rsq;
            rsq.x = fast_rsq(S.x);
            rsq.y = fast_rsq(S.y);
            v2f g  = pk_mul(mc, rsq);                  // -u
            v2f rt = pk_mul(S, rsq);                   // sqrt(S)
            v2f nD = pk_mul(D, cm1);
            v2f ea = pk_fma(g, g, nD);                 // u^2 - D  (<= 0)
            v2f ex;
            ex.x = __expf(ea.x);
            ex.y = __expf(ea.y);
            v2f e1 = erf2(pk_add(rt, g), c4, c3, c2, c1, c0);
            v2f e2 = erf2(g, c4, c3, c2, c1, c0);
            v2f e  = pk_fma(e2, cm1, e1);              // e1 - e2
            v2f q  = pk_mul(pk_mul(ex, rsq), e);
            s0 += (fminf(D.x, S.x) > 0.0f) ? q.x : 0.0f;
            s1 += (fminf(D.y, S.y) > 0.0f) ? q.y : 0.0f;
        }
        r = block_reduce<CTPB / 64>(s0 + s1, smr);
        slot = 2;
    } else if (bid < NINT + NFLT) {
        // ---- edge likelihood: -|od*(Zs_c-Zr_c) + d*(Zs_n-Zr_n)|^2 ----
        int e = (bid - NINT) * CTPB + tid;
        float seg = cp[1] - cp[0];
        float x   = ts[e] / seg;
        float kf  = floorf(x);
        int kappa = (int)kf;
        float d   = x - kf;
        float od  = 1.0f - d;
        int sb = snd[e] * 18, rbse = rcv[e] * 18;
        float ux = Z[sb + kappa]     - Z[rbse + kappa];
        float uy = Z[sb + 9 + kappa] - Z[rbse + 9 + kappa];
        float vx = Z[sb + kappa + 1]     - Z[rbse + kappa + 1];
        float vy = Z[sb + 9 + kappa + 1] - Z[rbse + 9 + kappa + 1];
        float wx = od * ux + d * vx;
        float wy = od * uy + d * vy;
        r = block_reduce<CTPB / 64>(-fmaf(wx, wx, wy * wy), smr);
        slot = 1;
    } else {
        // ---- prior ----
        int i = (bid - NINT - NFLT) * CTPB + tid;
        int n = nodes[i];
        const float* z = Z + n * 18;
        float s = 0.0f;
        #pragma unroll
        for (int d = 0; d < 2; ++d) {
            float prev = z[d * 9];
            s = fmaf(prev, prev, s);
            #pragma unroll
            for (int k = 1; k <= 8; ++k) {
                float cur = z[d * 9 + k];
                float df  = cur - prev;
                s = fmaf(df, df, s);
                prev = cur;
            }
        }
        r = block_reduce<CTPB / 64>(s, smr);
        slot = 0;
    }
    if (tid == 0) {
        if (mode) part[bid] = r;
        else      atomicAdd(part + slot, r);
    }
}

__global__ __launch_bounds__(CTPB) void k_final(const float* __restrict__ ws,
        int mode, const float* __restrict__ betap, const int* __restrict__ fsp,
        const float* __restrict__ cp, float* __restrict__ out,
        float n_entries, float bs) {
    __shared__ float sm0[CTPB / 64], sm1[CTPB / 64], sm2[CTPB / 64];
    int tid = threadIdx.x;
    float pr, fl, qq;
    if (mode) {
        float q = 0.0f, f = 0.0f, p = 0.0f;
        for (int i = tid; i < NBLK; i += CTPB) {
            float v = ws[i];
            if (i < NINT)             q += v;
            else if (i < NINT + NFLT) f += v;
            else                      p += v;
        }
        qq = block_reduce<CTPB / 64>(q, sm0);
        fl = block_reduce<CTPB / 64>(f, sm1);
        pr = block_reduce<CTPB / 64>(p, sm2);
    } else {
        pr = ws[0]; fl = ws[1]; qq = ws[2];
    }
    if (tid == 0) {
        float prior  = 10.0f * pr;
        float beta   = betap[0];
        float fs     = (float)fsp[0];
        float seg    = cp[1] - cp[0];
        // integral = 0.5(scan) * 0.5(erf pair) * sqrt(0.5)(sigma) * dt * Q
        float integral = 0.17677669529663687f * seg * qq;
        const float sqrt2pi = 2.5066282746310002f;
        float res = prior - beta * n_entries - fl + sqrt2pi * expf(beta) * integral;
        out[0] = (fs / bs) * res;
    }
}

extern "C" void kernel_launch(void* const* d_in, const int* in_sizes, int n_in,
                              void* d_out, int out_size, void* d_ws, size_t ws_size,
                              hipStream_t stream) {
    const float* Z    = (const float*)d_in[0];
    const float* beta = (const float*)d_in[1];
    const float* ts   = (const float*)d_in[2];
    const int*   snd  = (const int*)d_in[3];
    const int*   rcv  = (const int*)d_in[4];
    const int*   nodes= (const int*)d_in[5];
    const int*   su   = (const int*)d_in[6];
    const float* cp   = (const float*)d_in[7];
    const int*   fs   = (const int*)d_in[8];
    float* acc = (float*)d_ws;

    const int mode = (ws_size >= NBLK * sizeof(float)) ? 1 : 0;
    if (!mode) hipMemsetAsync(acc, 0, 3 * sizeof(float), stream);
    k_mega<<<NBLK, CTPB, 0, stream>>>(Z, ts, snd, rcv, nodes, su, cp, acc, mode);
    k_final<<<1, CTPB, 0, stream>>>(acc, mode, beta, fs, cp, (float*)d_out,
                                    (float)in_sizes[2], (float)in_sizes[5]);
}

// Round 5
// 170.984 us; speedup vs baseline: 1.0495x; 1.0495x over previous
//
#include <hip/hip_runtime.h>

#define EDGES   262144
#define CTPB    256
#define SCHUNK  256
#define NINT    2048   // 32 rblocks * 8 schunks * 8 segments
#define NFLT    (EDGES / CTPB)   // 1024
#define NPRI    16     // 4096 nodes / 256
#define NBLK    (NINT + NFLT + NPRI)

// All integral inputs pre-scaled by KS = sqrt(log2(e)) so that
//  - D' = L*D, S' = L*S, mc' = L*mc  (L = log2 e)
//  - ea = g'^2 - D' = L*(g^2 - D)  -> raw v_exp_f32 gives e^(g^2-D)
//  - erf args scale by sqrt(L); poly coefficients absorb 1/sqrt(L)
//  - q picks up factor 1/sqrt(L); folded into k_final's constant
#define KS      1.2011224087864498f
#define SCLAMP  0x1p-60f

__device__ __forceinline__ float fast_rsq(float x) { return __builtin_amdgcn_rsqf(x); }
__device__ __forceinline__ float fast_ex2(float x) { return __builtin_amdgcn_exp2f(x); }

// erf_s(x) = erf(x / sqrt(log2e)); odd deg-9, clamp |x| <= 2*sqrt(log2e).
// Base fit max abs err ~7e-4 in-range / ~4e-3 saturated.
__device__ __forceinline__ float erf_s(float x) {
    const float C0 =  0.93905091f;    //  1.127915  * k          (k = 1/sqrt(L))
    const float C1 = -0.21365741f;    // -0.370237  * k * ln2    (k^2 = ln2)
    const float C2 =  0.04006996f;    //  0.100174  * k * ln2^2
    const float C3 = -0.00458728f;    // -0.0165450 * k * ln2^3
    const float C4 =  0.00023054f;    //  0.0011996 * k * ln2^4
    const float CL =  2.4022448f;     //  2 * sqrt(L)
    float c = __builtin_amdgcn_fmed3f(x, -CL, CL);
    float t = c * c;
    float p = fmaf(t, fmaf(t, fmaf(t, fmaf(t, C4, C3), C2), C1), C0);
    return c * p;
}

// One pair: w = s-r (scaled), v = ds-dr (scaled); D=|w|^2, S=|v|^2, g=<v,w>*rsq
// term = exp2(g^2-D) * rsq * (erf_s(rt+g) - erf_s(g)),  rt = sqrt(S)
__device__ __forceinline__ float pair_term(float szx, float szy, float sdx, float sdy,
                                           float rzx, float rzy, float rdx, float rdy,
                                           float acc) {
    float wx = szx - rzx, wy = szy - rzy;
    float vx = sdx - rdx, vy = sdy - rdy;
    float D  = fmaf(wy, wy, wx * wx);
    float S  = fmaf(vy, vy, vx * vx);
    float mc = fmaf(vy, wy, vx * wx);          // <v,w> = -C
    float Sc = fmaxf(S, SCLAMP);               // self-pairs corrected in k_final
    float rsq = fast_rsq(Sc);
    float g  = mc * rsq;                       // -u
    float rt = Sc * rsq;                       // sqrt(Sc)
    float ex = fast_ex2(fmaf(g, g, -D));       // e^(g^2-D), <= ~1
    float e  = erf_s(rt + g) - erf_s(g);
    return fmaf(ex * rsq, e, acc);
}

template <int NW>
__device__ __forceinline__ float block_reduce(float v, float* sm) {
    #pragma unroll
    for (int o = 32; o > 0; o >>= 1) v += __shfl_down(v, o, 64);
    int lane = threadIdx.x & 63;
    int wid  = threadIdx.x >> 6;
    if (lane == 0) sm[wid] = v;
    __syncthreads();
    float r = 0.0f;
    if (threadIdx.x == 0) {
        #pragma unroll
        for (int w = 0; w < NW; ++w) r += sm[w];
    }
    return r;
}

__global__ __launch_bounds__(CTPB) void k_mega(const float* __restrict__ Z,
        const float* __restrict__ ts, const int* __restrict__ snd,
        const int* __restrict__ rcv, const int* __restrict__ nodes,
        const int* __restrict__ su, const float* __restrict__ cp,
        float* __restrict__ part, int mode) {
    __shared__ float4 sZx4[SCHUNK / 4];
    __shared__ float4 sZy4[SCHUNK / 4];
    __shared__ float4 sDx4[SCHUNK / 4];
    __shared__ float4 sDy4[SCHUNK / 4];
    __shared__ float smr[CTPB / 64];
    const int bid = blockIdx.x;
    const int tid = threadIdx.x;
    float r;
    int slot;

    if (bid < NINT) {
        const int k  = bid >> 8;
        const int sc = (bid >> 5) & 7;
        const int rb = bid & 31;
        {   // stage sender chunk (scaled) — op forms MUST match receiver path
            int n = su[sc * SCHUNK + tid];
            const float* z = Z + n * 18 + k;
            float zx = z[0] * KS, zy = z[9] * KS;
            ((float*)sZx4)[tid] = zx;
            ((float*)sZy4)[tid] = zy;
            ((float*)sDx4)[tid] = fmaf(z[1],  KS, -zx);
            ((float*)sDy4)[tid] = fmaf(z[10], KS, -zy);
        }
        const float* zr = Z + (rb * CTPB + tid) * 18 + k;
        float rzx = zr[0] * KS, rzy = zr[9] * KS;
        float rdx = fmaf(zr[1],  KS, -rzx);
        float rdy = fmaf(zr[10], KS, -rzy);
        __syncthreads();

        float s0 = 0.0f, s1 = 0.0f, s2 = 0.0f, s3 = 0.0f;
        #pragma unroll 2
        for (int i = 0; i < SCHUNK / 4; ++i) {
            float4 azx = sZx4[i];
            float4 azy = sZy4[i];
            float4 adx = sDx4[i];
            float4 ady = sDy4[i];
            s0 = pair_term(azx.x, azy.x, adx.x, ady.x, rzx, rzy, rdx, rdy, s0);
            s1 = pair_term(azx.y, azy.y, adx.y, ady.y, rzx, rzy, rdx, rdy, s1);
            s2 = pair_term(azx.z, azy.z, adx.z, ady.z, rzx, rzy, rdx, rdy, s2);
            s3 = pair_term(azx.w, azy.w, adx.w, ady.w, rzx, rzy, rdx, rdy, s3);
        }
        r = block_reduce<CTPB / 64>((s0 + s1) + (s2 + s3), smr);
        slot = 2;
    } else if (bid < NINT + NFLT) {
        // ---- edge likelihood: -|od*(Zs_c-Zr_c) + d*(Zs_n-Zr_n)|^2 ----
        int e = (bid - NINT) * CTPB + tid;
        float seg = cp[1] - cp[0];
        float x   = ts[e] / seg;
        float kf  = floorf(x);
        int kappa = (int)kf;
        float d   = x - kf;
        float od  = 1.0f - d;
        int sb = snd[e] * 18, rbse = rcv[e] * 18;
        float ux = Z[sb + kappa]     - Z[rbse + kappa];
        float uy = Z[sb + 9 + kappa] - Z[rbse + 9 + kappa];
        float vx = Z[sb + kappa + 1]     - Z[rbse + kappa + 1];
        float vy = Z[sb + 9 + kappa + 1] - Z[rbse + 9 + kappa + 1];
        float wx = od * ux + d * vx;
        float wy = od * uy + d * vy;
        r = block_reduce<CTPB / 64>(-fmaf(wx, wx, wy * wy), smr);
        slot = 1;
    } else {
        // ---- prior ----
        int i = (bid - NINT - NFLT) * CTPB + tid;
        int n = nodes[i];
        const float* z = Z + n * 18;
        float s = 0.0f;
        #pragma unroll
        for (int d = 0; d < 2; ++d) {
            float prev = z[d * 9];
            s = fmaf(prev, prev, s);
            #pragma unroll
            for (int k = 1; k <= 8; ++k) {
                float cur = z[d * 9 + k];
                float df  = cur - prev;
                s = fmaf(df, df, s);
                prev = cur;
            }
        }
        r = block_reduce<CTPB / 64>(s, smr);
        slot = 0;
    }
    if (tid == 0) {
        if (mode) part[bid] = r;
        else      atomicAdd(part + slot, r);
    }
}

__global__ __launch_bounds__(CTPB) void k_final(const float* __restrict__ ws,
        int mode, const float* __restrict__ betap, const int* __restrict__ fsp,
        const float* __restrict__ cp, float* __restrict__ out,
        float n_entries, float bs) {
    __shared__ float sm0[CTPB / 64], sm1[CTPB / 64], sm2[CTPB / 64];
    int tid = threadIdx.x;
    float pr, fl, qq;
    if (mode) {
        float q = 0.0f, f = 0.0f, p = 0.0f;
        for (int i = tid; i < NBLK; i += CTPB) {
            float v = ws[i];
            if (i < NINT)             q += v;
            else if (i < NINT + NFLT) f += v;
            else                      p += v;
        }
        qq = block_reduce<CTPB / 64>(q, sm0);
        fl = block_reduce<CTPB / 64>(f, sm1);
        pr = block_reduce<CTPB / 64>(p, sm2);
    } else {
        pr = ws[0]; fl = ws[1]; qq = ws[2];
    }
    if (tid == 0) {
        // Remove the 16384 self-pairs (D=S=0, masked in the reference) that the
        // clamped-S path added. Replicate the in-loop ops exactly: ex = exp2(0)=1,
        // e = erf_s(rt+0) - erf_s(0), contribution = (ex*rsq)*e.
        float rsqs = fast_rsq(SCLAMP);
        float rts  = SCLAMP * rsqs;
        float es   = erf_s(rts);
        double qself = (double)rsqs * (double)es;
        double Q = (double)qq - 16384.0 * qself;

        float prior  = 10.0f * pr;
        float beta   = betap[0];
        float fs     = (float)fsp[0];
        float seg    = cp[1] - cp[0];
        // integral = 0.5(scan)*0.5(erf pair)*sqrt(0.5)(sigma)*dt * Q * sqrt(L)
        const double CQ = 0.17677669529663687 * 1.2011224087864498;
        float integral = (float)(CQ * (double)seg * Q);
        const float sqrt2pi = 2.5066282746310002f;
        float res = prior - beta * n_entries - fl + sqrt2pi * expf(beta) * integral;
        out[0] = (fs / bs) * res;
    }
}

extern "C" void kernel_launch(void* const* d_in, const int* in_sizes, int n_in,
                              void* d_out, int out_size, void* d_ws, size_t ws_size,
                              hipStream_t stream) {
    const float* Z    = (const float*)d_in[0];
    const float* beta = (const float*)d_in[1];
    const float* ts   = (const float*)d_in[2];
    const int*   snd  = (const int*)d_in[3];
    const int*   rcv  = (const int*)d_in[4];
    const int*   nodes= (const int*)d_in[5];
    const int*   su   = (const int*)d_in[6];
    const float* cp   = (const float*)d_in[7];
    const int*   fs   = (const int*)d_in[8];
    float* acc = (float*)d_ws;

    const int mode = (ws_size >= NBLK * sizeof(float)) ? 1 : 0;
    if (!mode) hipMemsetAsync(acc, 0, 3 * sizeof(float), stream);
    k_mega<<<NBLK, CTPB, 0, stream>>>(Z, ts, snd, rcv, nodes, su, cp, acc, mode);
    k_final<<<1, CTPB, 0, stream>>>(acc, mode, beta, fs, cp, (float*)d_out,
                                    (float)in_sizes[2], (float)in_sizes[5]);
}